// Round 10
// baseline (178.792 us; speedup 1.0000x reference)
//
#include <hip/hip_runtime.h>
#include <hip/hip_bf16.h>
#include <math.h>

typedef __hip_bfloat16 bf16;
typedef _Float16 f16;
typedef __attribute__((ext_vector_type(8))) short bf16x8;
typedef __attribute__((ext_vector_type(8))) _Float16 f16x8;
typedef __attribute__((ext_vector_type(4))) float f32x4;
typedef __attribute__((ext_vector_type(4))) unsigned u32x4;

#define MFMA_BF(a,b,c) __builtin_amdgcn_mfma_f32_16x16x32_bf16((a),(b),(c),0,0,0)
#define MFMA_F16(a,b,c) __builtin_amdgcn_mfma_f32_16x16x32_f16((a),(b),(c),0,0,0)

__device__ __forceinline__ void load_lds16(const void* g, void* l) {
  __builtin_amdgcn_global_load_lds(
      (__attribute__((address_space(1))) void*)(g),
      (__attribute__((address_space(3))) void*)(l), 16, 0, 0);
}

// RTNE f32->bf16 pair pack
__device__ __forceinline__ unsigned pk_bf16(float a, float b) {
  unsigned ua = __builtin_bit_cast(unsigned, a);
  unsigned ub = __builtin_bit_cast(unsigned, b);
  ua += 0x7fffu + ((ua >> 16) & 1u);
  ub += 0x7fffu + ((ub >> 16) & 1u);
  return (ua >> 16) | (ub & 0xffff0000u);
}

// ---------------- fused fp32 -> bf16 convert (x, W_qkv, W_out) ----------------
__global__ void cvt_all(const float* __restrict__ x, const float* __restrict__ wq,
                        const float* __restrict__ wo, unsigned* __restrict__ xb,
                        unsigned* __restrict__ wqb, unsigned* __restrict__ wob) {
  int i = blockIdx.x * blockDim.x + threadIdx.x;  // float4 index, 2097152 total
  const float* src;
  unsigned* dst;
  int off;
  if (i < 1048576) { src = x; dst = xb; off = i; }
  else if (i < 1048576 + 786432) { src = wq; dst = wqb; off = i - 1048576; }
  else { src = wo; dst = wob; off = i - (1048576 + 786432); }
  float4 v = reinterpret_cast<const float4*>(src)[off];
  uint2 u;
  u.x = pk_bf16(v.x, v.y);
  u.y = pk_bf16(v.z, v.w);
  reinterpret_cast<uint2*>(dst)[off] = u;
}

// ---------------- merged QKV GEMM: C[M,3072] = A[M,1024] * Wqkv^T ----------------
// 3-deep pipeline, partial vmcnt waits, XOR-swizzled staging (0 conflicts).
__global__ __launch_bounds__(256, 2)
void gemm_qkv(const bf16* __restrict__ A, const bf16* __restrict__ B,
              bf16* __restrict__ outq, bf16* __restrict__ outk,
              f16* __restrict__ outv) {
  __shared__ __align__(16) bf16 As[3][128 * 32];
  __shared__ __align__(16) bf16 Bs[3][128 * 32];
  const int K = 1024;
  const int tid = threadIdx.x;
  const int w = tid >> 6;
  const int lane = tid & 63;
  const int quad = lane >> 4;
  const int col = lane & 15;
  const int waveM = w >> 1;
  const int waveN = w & 1;
  const int bm = blockIdx.y * 128;
  const int bn = blockIdx.x * 128;

  f32x4 acc[4][4] = {};
  const int srow = lane >> 2;
  const int skoff = (((lane & 3) ^ ((srow >> 1) & 3))) * 8;
  const int swq = (quad ^ ((col >> 1) & 3)) * 8;

  auto stage = [&](int k0, int sb) {
#pragma unroll
    for (int p = 0; p < 2; ++p) {
      int r = p * 64 + w * 16 + srow;
      load_lds16(A + (size_t)(bm + r) * K + k0 + skoff,
                 (char*)As + sb * 8192 + p * 4096 + w * 1024);
      load_lds16(B + (size_t)(bn + r) * K + k0 + skoff,
                 (char*)Bs + sb * 8192 + p * 4096 + w * 1024);
    }
  };

  stage(0, 0);
  stage(32, 1);

  int cb = 0;
  for (int k0 = 0; k0 < K; k0 += 32) {
    if (k0 + 32 < K) __asm__ volatile("s_waitcnt vmcnt(4)" ::: "memory");
    else             __asm__ volatile("s_waitcnt vmcnt(0)" ::: "memory");
    __asm__ volatile("s_barrier" ::: "memory");
    if (k0 + 64 < K) {
      int nb = cb + 2; if (nb >= 3) nb -= 3;
      stage(k0 + 64, nb);
    }
    const bf16* at = &As[cb][0];
    const bf16* bt = &Bs[cb][0];
    bf16x8 af[4], bfr[4];
#pragma unroll
    for (int i = 0; i < 4; ++i)
      af[i] = *reinterpret_cast<const bf16x8*>(at + (waveM * 64 + i * 16 + col) * 32 + swq);
#pragma unroll
    for (int j = 0; j < 4; ++j)
      bfr[j] = *reinterpret_cast<const bf16x8*>(bt + (waveN * 64 + j * 16 + col) * 32 + swq);
#pragma unroll
    for (int i = 0; i < 4; ++i)
#pragma unroll
      for (int j = 0; j < 4; ++j)
        acc[i][j] = MFMA_BF(af[i], bfr[j], acc[i][j]);
    cb = (cb == 2) ? 0 : cb + 1;
  }

  if (bn < 2048) {
    const float NEGK = -0.4152410118f;  // -log2(10000)/32
    const float C1 = 0.1803368799f;     // 0.125 * log2(e)
    const float sgn = (col & 1) ? 1.0f : -1.0f;
#pragma unroll
    for (int j = 0; j < 4; ++j) {
      const int n0 = bn + waveN * 64 + j * 16;
      const int sel = n0 >> 10;                 // 0=q, 1=k
      const int hh = (n0 & 1023) >> 6;
      const int dd = (n0 & 63) + col;
      bf16* outp = sel ? outk : outq;
      const float post = sel ? 1.0f : C1;
      const float invf = __builtin_amdgcn_exp2f((float)((n0 & 31) + col) * NEGK);
#pragma unroll
      for (int i = 0; i < 4; ++i) {
#pragma unroll
        for (int r = 0; r < 4; ++r) {
          int m = bm + waveM * 64 + i * 16 + quad * 4 + r;
          int b = m >> 11, t = m & 2047;
          float v = acc[i][j][r];
          float partner = __shfl_xor(v, 1);
          float ang = (float)t * invf;
          float res = (v * __cosf(ang) + sgn * partner * __sinf(ang)) * post;
          outp[((size_t)(b * 16 + hh) * 2048 + t) * 64 + dd] = __float2bfloat16(res);
        }
      }
    }
  } else {
    const int b = bm >> 11;
    const int tt0 = (bm & 2047) + waveM * 64;
#pragma unroll
    for (int j = 0; j < 4; ++j) {
      const int n0 = bn + waveN * 64 + j * 16;
      const int hh = (n0 & 1023) >> 6;
      const int dd = (n0 & 63) + col;
      f16* dst = outv + (size_t)(b * 16 + hh) * 131072 + (size_t)dd * 2048;
#pragma unroll
      for (int i = 0; i < 4; ++i) {
        uint2 pk;
        pk.x = __builtin_bit_cast(unsigned, __builtin_amdgcn_cvt_pkrtz(acc[i][j][0], acc[i][j][1]));
        pk.y = __builtin_bit_cast(unsigned, __builtin_amdgcn_cvt_pkrtz(acc[i][j][2], acc[i][j][3]));
        *reinterpret_cast<uint2*>(dst + tt0 + i * 16 + quad * 4) = pk;
      }
    }
  }
}

// ---------------- output GEMM: out[4096,1024] = y[4096,1024] * Wout^T ----------------
__global__ __launch_bounds__(256, 2)
void gemm_out(const bf16* __restrict__ A, const bf16* __restrict__ B,
              float* __restrict__ outf) {
  __shared__ __align__(16) bf16 As[3][64 * 32];
  __shared__ __align__(16) bf16 Bs[3][128 * 32];
  const int K = 1024;
  const int tid = threadIdx.x;
  const int w = tid >> 6;
  const int lane = tid & 63;
  const int quad = lane >> 4;
  const int col = lane & 15;
  const int bm = blockIdx.y * 64;
  const int bn = blockIdx.x * 128;

  f32x4 acc[4][2] = {};
  const int srow = lane >> 2;
  const int skoff = (((lane & 3) ^ ((srow >> 1) & 3))) * 8;
  const int swq = (quad ^ ((col >> 1) & 3)) * 8;

  auto stage = [&](int k0, int sb) {
    load_lds16(A + (size_t)(bm + w * 16 + srow) * K + k0 + skoff,
               (char*)As + sb * 4096 + w * 1024);
#pragma unroll
    for (int p = 0; p < 2; ++p)
      load_lds16(B + (size_t)(bn + p * 64 + w * 16 + srow) * K + k0 + skoff,
                 (char*)Bs + sb * 8192 + p * 4096 + w * 1024);
  };

  stage(0, 0);
  stage(32, 1);

  int cb = 0;
  for (int k0 = 0; k0 < K; k0 += 32) {
    if (k0 + 32 < K) __asm__ volatile("s_waitcnt vmcnt(3)" ::: "memory");
    else             __asm__ volatile("s_waitcnt vmcnt(0)" ::: "memory");
    __asm__ volatile("s_barrier" ::: "memory");
    if (k0 + 64 < K) {
      int nb = cb + 2; if (nb >= 3) nb -= 3;
      stage(k0 + 64, nb);
    }
    const bf16* at = &As[cb][0];
    const bf16* bt = &Bs[cb][0];
    bf16x8 af[4], bfr[2];
#pragma unroll
    for (int i = 0; i < 4; ++i)
      af[i] = *reinterpret_cast<const bf16x8*>(at + (i * 16 + col) * 32 + swq);
#pragma unroll
    for (int j = 0; j < 2; ++j)
      bfr[j] = *reinterpret_cast<const bf16x8*>(bt + (w * 32 + j * 16 + col) * 32 + swq);
#pragma unroll
    for (int i = 0; i < 4; ++i)
#pragma unroll
      for (int j = 0; j < 2; ++j)
        acc[i][j] = MFMA_BF(af[i], bfr[j], acc[i][j]);
    cb = (cb == 2) ? 0 : cb + 1;
  }

#pragma unroll
  for (int i = 0; i < 4; ++i)
#pragma unroll
    for (int j = 0; j < 2; ++j) {
      const int n0 = bn + w * 32 + j * 16;
#pragma unroll
      for (int r = 0; r < 4; ++r) {
        int m = bm + i * 16 + quad * 4 + r;
        outf[(size_t)m * 1024 + n0 + col] = acc[i][j][r];
      }
    }
}

// ---------------- flash attention: 2x2 wave specialization ----------------
// grid (16 qtiles, 32 bh); 4 waves: kg = w&1 (32-key half), qg = w>>1 (64 q).
// Per wave-iter: 8 b128 LDS reads for 32 MFMAs (4x better than R9).
// kappa: LDS K-row kg*32+kt*16+4g+i holds chunk-key kg*32+8g+4kt+i, so S^T
// C-regs (key = kg*32+quad*8+kt*4+r) ARE the PV B-frag slots j=kt*4+r.
// V identity [d][key]; V-frag at key-offset kg*32+quad*8. XOR-row swizzle
// keeps everything 2-way (free). Partial O/l merged across kg-partners via
// one epilogue LDS exchange (exact fp32 adds). Fixed-offset softmax p=exp2(s).
__global__ __launch_bounds__(256, 2)
void attn_kernel(const bf16* __restrict__ qh, const bf16* __restrict__ kh,
                 const f16* __restrict__ vt, bf16* __restrict__ y) {
  __shared__ __align__(16) bf16 Ks[3][64 * 64];
  __shared__ __align__(16) f16 Vs[3][64 * 64];

  const int bh = blockIdx.y;
  const int w = threadIdx.x >> 6;
  const int lane = threadIdx.x & 63;
  const int quad = lane >> 4;
  const int col = lane & 15;
  const int kg = w & 1;
  const int qg = w >> 1;

  // ---- Q fragments: 4 frags (64 q rows) x 2 d-chains ----
  const int qbase = blockIdx.x * 128 + qg * 64 + col;
  bf16x8 qf[4][2];
#pragma unroll
  for (int f = 0; f < 4; ++f)
#pragma unroll
    for (int c = 0; c < 2; ++c)
      qf[f][c] = *reinterpret_cast<const bf16x8*>(
          qh + ((size_t)bh * 2048 + qbase + f * 16) * 64 + c * 32 + quad * 8);

  const int s8 = lane >> 3;
  const int blk = (lane & 7) ^ s8;     // swizzled 16B block (XOR by row&7 = s8)
  const bf16* kg_ptr = kh + (size_t)bh * 2048 * 64;
  const f16* vg_ptr = vt + (size_t)bh * 64 * 2048;
  // kappa: key for LDS row rho = w*16 + L*8 + s8:
  //   kappa = (w>>1)*32 + (w&1)*4 + 16L + 8*(s8>>2) + (s8&3)
  const int ks0 = (w >> 1) * 32 + (w & 1) * 4 + 8 * (s8 >> 2) + (s8 & 3);
  const int ks1 = ks0 + 16;
  const int vrow0 = w * 16 + s8;       // V rows = d, identity keys

  const int csw = col & 7;
  const int sw0 = (quad ^ csw) * 8;            // K chain-0 block
  const int sw1 = ((quad + 4) ^ csw) * 8;      // K chain-1 block
  const int vsw = ((kg * 4 + quad) ^ csw) * 8; // V key-block for this kg
  const int krow = kg * 32;                    // K tile base row for this kg

  f32x4 O[4][4] = {};   // [jt d-tile][qf]
  float l[4] = {};      // per q-frag, keys quad*8+0..7 (both kt)

  auto stage = [&](int kn, int sb) {
    char* kb = (char*)Ks + sb * 8192 + w * 2048;
    char* vb = (char*)Vs + sb * 8192 + w * 2048;
    load_lds16(kg_ptr + (size_t)(kn + ks0) * 64 + blk * 8, kb);
    load_lds16(kg_ptr + (size_t)(kn + ks1) * 64 + blk * 8, kb + 1024);
    load_lds16(vg_ptr + (size_t)vrow0 * 2048 + kn + blk * 8, vb);
    load_lds16(vg_ptr + (size_t)(vrow0 + 8) * 2048 + kn + blk * 8, vb + 1024);
  };

  stage(0, 0);
  stage(64, 1);

  int cb = 0;
  for (int kc = 0; kc < 2048; kc += 64) {
    if (kc + 64 < 2048) __asm__ volatile("s_waitcnt vmcnt(4)" ::: "memory");
    else                __asm__ volatile("s_waitcnt vmcnt(0)" ::: "memory");
    __asm__ volatile("s_barrier" ::: "memory");
    if (kc + 128 < 2048) {
      int nb = cb + 2; if (nb >= 3) nb -= 3;
      stage(kc + 128, nb);
    }

    const bf16* kt_p = &Ks[cb][0];
    const f16* vtile = &Vs[cb][0];

    // ---- K frags: 2 key-tiles x 2 chains ----
    bf16x8 kf[2][2];
#pragma unroll
    for (int t = 0; t < 2; ++t) {
      kf[t][0] = *reinterpret_cast<const bf16x8*>(kt_p + (krow + t * 16 + col) * 64 + sw0);
      kf[t][1] = *reinterpret_cast<const bf16x8*>(kt_p + (krow + t * 16 + col) * 64 + sw1);
    }

    // ---- S^T = K . Q^T : D[key][q], 2 key-tiles x 4 q-frags ----
    f32x4 s[2][4];
#pragma unroll
    for (int t = 0; t < 2; ++t)
#pragma unroll
      for (int f = 0; f < 4; ++f) {
        f32x4 a = {};
        a = MFMA_BF(kf[t][0], qf[f][0], a);
        a = MFMA_BF(kf[t][1], qf[f][1], a);
        s[t][f] = a;
      }

    // ---- softmax + in-register P pack: slots j = kt*4 + r ----
    f16x8 pf[4];
#pragma unroll
    for (int f = 0; f < 4; ++f) {
      float p00 = __builtin_amdgcn_exp2f(s[0][f][0]);
      float p01 = __builtin_amdgcn_exp2f(s[0][f][1]);
      float p02 = __builtin_amdgcn_exp2f(s[0][f][2]);
      float p03 = __builtin_amdgcn_exp2f(s[0][f][3]);
      float p10 = __builtin_amdgcn_exp2f(s[1][f][0]);
      float p11 = __builtin_amdgcn_exp2f(s[1][f][1]);
      float p12 = __builtin_amdgcn_exp2f(s[1][f][2]);
      float p13 = __builtin_amdgcn_exp2f(s[1][f][3]);
      l[f] += ((p00 + p01) + (p02 + p03)) + ((p10 + p11) + (p12 + p13));
      u32x4 pk;
      pk.x = __builtin_bit_cast(unsigned, __builtin_amdgcn_cvt_pkrtz(p00, p01));
      pk.y = __builtin_bit_cast(unsigned, __builtin_amdgcn_cvt_pkrtz(p02, p03));
      pk.z = __builtin_bit_cast(unsigned, __builtin_amdgcn_cvt_pkrtz(p10, p11));
      pk.w = __builtin_bit_cast(unsigned, __builtin_amdgcn_cvt_pkrtz(p12, p13));
      pf[f] = __builtin_bit_cast(f16x8, pk);
    }

    // ---- O^T += V . P^T : 4 d-tiles x 4 q-frags, K=32 (this kg's keys) ----
#pragma unroll
    for (int jt = 0; jt < 4; ++jt) {
      f16x8 vf = *reinterpret_cast<const f16x8*>(vtile + (jt * 16 + col) * 64 + vsw);
#pragma unroll
      for (int f = 0; f < 4; ++f)
        O[jt][f] = MFMA_F16(vf, pf[f], O[jt][f]);
    }
    cb = (cb == 2) ? 0 : cb + 1;
  }

  // ---- epilogue: quad-reduce l, cross-kg merge via LDS, normalize, store ----
#pragma unroll
  for (int f = 0; f < 4; ++f) {
    l[f] += __shfl_xor(l[f], 16, 64);
    l[f] += __shfl_xor(l[f], 32, 64);
  }

  float* xb = (float*)&Ks[0][0];   // 48 KB reuse; need 2 x 17408 B
  if (kg == 1) {
    float* dst = xb + qg * 4352 + lane * 68;
#pragma unroll
    for (int jt = 0; jt < 4; ++jt)
#pragma unroll
      for (int f = 0; f < 4; ++f)
        *reinterpret_cast<f32x4*>(dst + (jt * 4 + f) * 4) = O[jt][f];
#pragma unroll
    for (int f = 0; f < 4; ++f) dst[64 + f] = l[f];
  }
  __syncthreads();
  if (kg == 0) {
    const float* src = xb + qg * 4352 + lane * 68;
    const int b = bh >> 4, h = bh & 15;
#pragma unroll
    for (int f = 0; f < 4; ++f) {
      float lv = l[f] + src[64 + f];
      float inv = 1.0f / lv;
      int q = qbase - col + f * 16 + col;   // = qbase + f*16
      size_t base = ((size_t)b * 2048 + q) * 1024 + h * 64;
#pragma unroll
      for (int jt = 0; jt < 4; ++jt) {
        f32x4 o = O[jt][f] + *reinterpret_cast<const f32x4*>(src + (jt * 4 + f) * 4);
        uint2 pk2;
        pk2.x = pk_bf16(o[0] * inv, o[1] * inv);
        pk2.y = pk_bf16(o[2] * inv, o[3] * inv);
        *reinterpret_cast<uint2*>((unsigned short*)y + base + jt * 16 + quad * 4) = pk2;
      }
    }
  }
}

extern "C" void kernel_launch(void* const* d_in, const int* in_sizes, int n_in,
                              void* d_out, int out_size, void* d_ws, size_t ws_size,
                              hipStream_t stream) {
  const float* x    = (const float*)d_in[0];
  const float* wqkv = (const float*)d_in[1];
  const float* wout = (const float*)d_in[2];
  float* out = (float*)d_out;
  char* ws = (char*)d_ws;

  bf16* xb    = (bf16*)(ws);                        // 8 MB
  bf16* wqkvb = (bf16*)(ws + (size_t)(8 << 20));    // 6 MB
  bf16* woutb = (bf16*)(ws + (size_t)(14 << 20));   // 2 MB
  bf16* qh    = (bf16*)(ws + (size_t)(16 << 20));   // 8 MB
  bf16* kh    = (bf16*)(ws + (size_t)(24 << 20));   // 8 MB
  f16*  vt    = (f16*) (ws + (size_t)(32 << 20));   // 8 MB
  bf16* y     = (bf16*)(ws + (size_t)(40 << 20));   // 8 MB

  cvt_all<<<8192, 256, 0, stream>>>(x, wqkv, wout,
                                    (unsigned*)xb, (unsigned*)wqkvb, (unsigned*)woutb);
  gemm_qkv<<<dim3(24, 32), 256, 0, stream>>>(xb, wqkvb, qh, kh, vt);
  attn_kernel<<<dim3(16, 32), 256, 0, stream>>>(qh, kh, vt, y);
  gemm_out<<<dim3(8, 64), 256, 0, stream>>>(y, woutb, out);
}